// Round 1
// baseline (990.963 us; speedup 1.0000x reference)
//
#include <hip/hip_runtime.h>
#include <math.h>

// GCN fused kernel for MI355X (gfx950).
// Problem: B=4096, N=116 nodes, F_IN=116, HID=256, OUT=2.
//   h1 = relu(support @ (x @ W1) + b1)        [B,116,256]
//   h2 = relu(support @ (h1 @ W2) + b2)       [B,116,4]
//   r  = relu(h2.flat @ Wr1 + br1)            [B,64]
//   out= log_softmax(r @ Wr2 + br2)           [B,2]
// Kernel 1: one block per batch element, fully fused through h2 -> ws.
// Kernel 2: readout from ws -> d_out.

#define BDIM 256

constexpr int Bsz  = 4096;
constexpr int Nn   = 116;   // nodes
constexpr int Fin  = 116;   // input features
constexpr int HID  = 256;
constexpr int NC   = 64;    // HID chunk
constexpr int SK   = 136;   // bf16 row stride for K<=128 buffers (bank rotation, rows 16B aligned)
constexpr int SH   = 264;   // bf16 row stride for K=256 buffers
constexpr int NELEM = Nn * Fin;   // 13456
constexpr int NF4   = NELEM / 4;  // 3364  (116%4==0 so float4 never straddles rows)
constexpr int TOFF  = 4352;       // tT offset (elements) inside scb

typedef __bf16 bf16;
typedef __bf16 bf16x4 __attribute__((ext_vector_type(4)));
typedef __bf16 bf16x8 __attribute__((ext_vector_type(8)));
typedef float  floatx4 __attribute__((ext_vector_type(4)));

// MFMA 16x16x32 bf16 fragment layout (HW-verified per guide):
//   A-frag: A[m = lane&15][k = (lane>>4)*8 + j], j=0..7 contiguous  -> ds_read_b128
//   B-frag: B^T[n = lane&15][k = (lane>>4)*8 + j]
//   C/D:    col = lane&15, row = (lane>>4)*4 + reg

__global__ __launch_bounds__(BDIM) void gcn_fused(
    const float* __restrict__ X, const float* __restrict__ SUPP,
    const float* __restrict__ W1, const float* __restrict__ B1v,
    const float* __restrict__ W2, const float* __restrict__ B2v,
    float* __restrict__ WS)
{
  // 148,288 B total LDS -> 1 block/CU
  __shared__ bf16 sx  [128 * SK];  // x_b   [m][k]   34816 B
  __shared__ bf16 ssup[128 * SK];  // sup_b [m][k]   34816 B
  __shared__ bf16 sh1 [116 * SH];  // h1    [m][hid] 61248 B (A-frag reads may run past end: harmless, rows>=116 discarded)
  __shared__ bf16 scb [64 * SK];   // chunk buf: W1T chunk / xwT chunk; later W2T @0 (16*SH) + tT @TOFF (16*SK). 17408 B

  const int b    = blockIdx.x;
  const int tid  = threadIdx.x;
  const int wid  = tid >> 6;
  const int lane = tid & 63;
  const int quad = lane >> 4;
  const int l16  = lane & 15;

  // ---- stage x_b, support_b (fp32 -> bf16), coalesced float4 ----
  const float4* xg = (const float4*)(X    + (size_t)b * NELEM);
  const float4* sg = (const float4*)(SUPP + (size_t)b * NELEM);
  for (int i = tid; i < NF4; i += BDIM) {
    int m  = i / 29;             // row (node)
    int kq = (i - m * 29) * 4;   // col
    float4 v = xg[i];
    bf16x4 p; p[0]=(bf16)v.x; p[1]=(bf16)v.y; p[2]=(bf16)v.z; p[3]=(bf16)v.w;
    *(bf16x4*)&sx[m * SK + kq] = p;
    float4 u = sg[i];
    bf16x4 q; q[0]=(bf16)u.x; q[1]=(bf16)u.y; q[2]=(bf16)u.z; q[3]=(bf16)u.w;
    *(bf16x4*)&ssup[m * SK + kq] = q;
  }
  // pad rows 116..127 of sx/ssup are never written: garbage only pollutes
  // output rows >=116 which are never stored.

  const int wm = (wid & 1) * 64;   // wave m-base (2x2 wave grid)
  const int wn = (wid >> 1) * 32;  // wave n-base within chunk

  // ---- chunk loop over HID ----
  for (int c = 0; c < 4; ++c) {
    // stage W1^T chunk: scb[n][k] = W1[k][c*64+n]; zero K-pad (k>=116)
    for (int i = tid; i < 64 * 128; i += BDIM) {
      int k = i >> 6, n = i & 63;
      float w = (k < Fin) ? W1[k * HID + c * NC + n] : 0.f;
      scb[n * SK + k] = (bf16)w;
    }
    __syncthreads();

    // GEMM1: xw_c = x @ W1_c   (M=128pad, N=64, K=128pad)
    floatx4 acc[4][2];
#pragma unroll
    for (int mt = 0; mt < 4; ++mt)
#pragma unroll
      for (int nt = 0; nt < 2; ++nt) acc[mt][nt] = (floatx4)0.f;
#pragma unroll
    for (int ks = 0; ks < 4; ++ks) {
      int k0 = ks * 32 + quad * 8;
      bf16x8 af[4], bfr[2];
#pragma unroll
      for (int mt = 0; mt < 4; ++mt)
        af[mt] = *(const bf16x8*)&sx[(wm + mt * 16 + l16) * SK + k0];
#pragma unroll
      for (int nt = 0; nt < 2; ++nt)
        bfr[nt] = *(const bf16x8*)&scb[(wn + nt * 16 + l16) * SK + k0];
#pragma unroll
      for (int mt = 0; mt < 4; ++mt)
#pragma unroll
        for (int nt = 0; nt < 2; ++nt)
          acc[mt][nt] = __builtin_amdgcn_mfma_f32_16x16x32_bf16(af[mt], bfr[nt], acc[mt][nt], 0, 0, 0);
    }
    __syncthreads();  // all W1T reads done before overwrite

    // write xw^T into scb: scb[n][m] = xw[m][n]; zero m-pad (protects GEMM2 K-pad)
#pragma unroll
    for (int mt = 0; mt < 4; ++mt)
#pragma unroll
      for (int nt = 0; nt < 2; ++nt) {
        int mb = wm + mt * 16 + quad * 4;
        int n  = wn + nt * 16 + l16;
        floatx4 a = acc[mt][nt];
        bf16x4 p;
        if (mb < Nn) { p[0]=(bf16)a[0]; p[1]=(bf16)a[1]; p[2]=(bf16)a[2]; p[3]=(bf16)a[3]; }
        else         { p[0]=p[1]=p[2]=p[3]=(bf16)0.f; }
        *(bf16x4*)&scb[n * SK + mb] = p;  // mb multiple of 4; 116%4==0 so packs never straddle
      }
    __syncthreads();

    // GEMM2: h1_c = relu(sup @ xw_c + b1_c)
#pragma unroll
    for (int mt = 0; mt < 4; ++mt)
#pragma unroll
      for (int nt = 0; nt < 2; ++nt) acc[mt][nt] = (floatx4)0.f;
#pragma unroll
    for (int ks = 0; ks < 4; ++ks) {
      int k0 = ks * 32 + quad * 8;
      bf16x8 af[4], bfr[2];
#pragma unroll
      for (int mt = 0; mt < 4; ++mt)
        af[mt] = *(const bf16x8*)&ssup[(wm + mt * 16 + l16) * SK + k0];
#pragma unroll
      for (int nt = 0; nt < 2; ++nt)
        bfr[nt] = *(const bf16x8*)&scb[(wn + nt * 16 + l16) * SK + k0];
#pragma unroll
      for (int mt = 0; mt < 4; ++mt)
#pragma unroll
        for (int nt = 0; nt < 2; ++nt)
          acc[mt][nt] = __builtin_amdgcn_mfma_f32_16x16x32_bf16(af[mt], bfr[nt], acc[mt][nt], 0, 0, 0);
    }
#pragma unroll
    for (int mt = 0; mt < 4; ++mt)
#pragma unroll
      for (int nt = 0; nt < 2; ++nt) {
        int mb  = wm + mt * 16 + quad * 4;
        int col = c * NC + wn + nt * 16 + l16;
        float bb = B1v[col];
        floatx4 a = acc[mt][nt];
#pragma unroll
        for (int r = 0; r < 4; ++r) {
          int m = mb + r;
          if (m < Nn) sh1[m * SH + col] = (bf16)fmaxf(a[r] + bb, 0.f);
        }
      }
    __syncthreads();  // scb reads done before next chunk staging; h1 visible
  }

  // ---- stage W2^T: scb[n][k] = W2[k][n], k=0..255 exact (no K-pad) ----
  for (int i = tid; i < HID * 4; i += BDIM) {
    int k = i >> 2, n = i & 3;
    scb[n * SH + k] = (bf16)W2[i];
  }
  __syncthreads();

  // GEMM3: t = h1 @ W2   (M=128pad, N=16pad(4), K=256) ; wave owns 32 rows
  floatx4 acc3[2]; acc3[0] = (floatx4)0.f; acc3[1] = (floatx4)0.f;
#pragma unroll
  for (int ks = 0; ks < 8; ++ks) {
    int k0 = ks * 32 + quad * 8;
    bf16x8 bfr = *(const bf16x8*)&scb[l16 * SH + k0];  // rows 4..15 garbage -> discarded cols
#pragma unroll
    for (int mt = 0; mt < 2; ++mt) {
      bf16x8 af = *(const bf16x8*)&sh1[(wid * 32 + mt * 16 + l16) * SH + k0];
      acc3[mt] = __builtin_amdgcn_mfma_f32_16x16x32_bf16(af, bfr, acc3[mt], 0, 0, 0);
    }
  }
  // write t^T (zero m-pad); region disjoint from W2T reads -> no barrier needed before writes
#pragma unroll
  for (int mt = 0; mt < 2; ++mt) {
    int mb = wid * 32 + mt * 16 + quad * 4;
    floatx4 a = acc3[mt];
    bf16x4 p;
    if (mb < Nn) { p[0]=(bf16)a[0]; p[1]=(bf16)a[1]; p[2]=(bf16)a[2]; p[3]=(bf16)a[3]; }
    else         { p[0]=p[1]=p[2]=p[3]=(bf16)0.f; }
    if (l16 < 4) *(bf16x4*)&scb[TOFF + l16 * SK + mb] = p;
  }
  __syncthreads();

  // GEMM4: h2 = relu(sup @ t + b2)   (M=128pad, N=16pad(4), K=128pad)
  floatx4 acc4[2]; acc4[0] = (floatx4)0.f; acc4[1] = (floatx4)0.f;
#pragma unroll
  for (int ks = 0; ks < 4; ++ks) {
    int k0 = ks * 32 + quad * 8;
    bf16x8 bfr = *(const bf16x8*)&scb[TOFF + l16 * SK + k0];
#pragma unroll
    for (int mt = 0; mt < 2; ++mt) {
      bf16x8 af = *(const bf16x8*)&ssup[(wid * 32 + mt * 16 + l16) * SK + k0];
      acc4[mt] = __builtin_amdgcn_mfma_f32_16x16x32_bf16(af, bfr, acc4[mt], 0, 0, 0);
    }
  }
  float* wsb = WS + (size_t)b * (Nn * 4);
  if (l16 < 4) {
    float bb = B2v[l16];
#pragma unroll
    for (int mt = 0; mt < 2; ++mt) {
      int mb = wid * 32 + mt * 16 + quad * 4;
      floatx4 a = acc4[mt];
#pragma unroll
      for (int r = 0; r < 4; ++r) {
        int m = mb + r;
        if (m < Nn) wsb[m * 4 + l16] = fmaxf(a[r] + bb, 0.f);  // flat[b, m*4+o]
      }
    }
  }
}

// ---- readout: r = relu(flat@Wr1+br1); out = log_softmax(r@Wr2+br2) ----
// 256 blocks x 256 threads; each block: 16 batch rows, Wr1 staged in LDS once.
__global__ __launch_bounds__(BDIM) void gcn_readout(
    const float* __restrict__ WS, const float* __restrict__ Wr1,
    const float* __restrict__ br1, const float* __restrict__ Wr2,
    const float* __restrict__ br2, float* __restrict__ OUTP)
{
  __shared__ float sw[464 * 64];   // Wr1 row-major [k][j]  118784 B
  __shared__ float sf[16 * 464];   // flat rows             29696 B
  const int tid  = threadIdx.x;
  const int lane = tid & 63;
  const int wid  = tid >> 6;
  const int b0   = blockIdx.x * 16;

  for (int i = tid; i < 7424; i += BDIM)  // 464*64/4
    ((float4*)sw)[i] = ((const float4*)Wr1)[i];
  for (int i = tid; i < 1856; i += BDIM)  // 16*464/4
    ((float4*)sf)[i] = ((const float4*)(WS + (size_t)b0 * 464))[i];
  __syncthreads();

  // wave w handles b0 + wid + {0,4,8,12}; thread lane = output unit j
  float a0 = 0.f, a1 = 0.f, a2 = 0.f, a3 = 0.f;
  const float* f0 = sf + (wid + 0) * 464;
  const float* f1 = sf + (wid + 4) * 464;
  const float* f2 = sf + (wid + 8) * 464;
  const float* f3 = sf + (wid + 12) * 464;
  for (int k = 0; k < 464; ++k) {
    float wv = sw[k * 64 + lane];      // conflict-free
    a0 = fmaf(f0[k], wv, a0);          // broadcast reads
    a1 = fmaf(f1[k], wv, a1);
    a2 = fmaf(f2[k], wv, a2);
    a3 = fmaf(f3[k], wv, a3);
  }
  float rb  = br1[lane];
  float w20 = Wr2[lane * 2 + 0], w21 = Wr2[lane * 2 + 1];
  float bb0 = br2[0], bb1 = br2[1];
  float accs[4] = {a0, a1, a2, a3};
#pragma unroll
  for (int g = 0; g < 4; ++g) {
    float r  = fmaxf(accs[g] + rb, 0.f);
    float p0 = r * w20, p1 = r * w21;
#pragma unroll
    for (int off = 32; off > 0; off >>= 1) {
      p0 += __shfl_xor(p0, off, 64);
      p1 += __shfl_xor(p1, off, 64);
    }
    float l0 = p0 + bb0, l1 = p1 + bb1;
    float mx = fmaxf(l0, l1);
    float lse = mx + logf(expf(l0 - mx) + expf(l1 - mx));
    int bidx = b0 + wid + 4 * g;
    if (lane < 2) OUTP[(size_t)bidx * 2 + lane] = (lane ? l1 : l0) - lse;
  }
}

extern "C" void kernel_launch(void* const* d_in, const int* in_sizes, int n_in,
                              void* d_out, int out_size, void* d_ws, size_t ws_size,
                              hipStream_t stream) {
  const float* X    = (const float*)d_in[0];
  const float* SUPP = (const float*)d_in[1];
  const float* W1   = (const float*)d_in[2];
  const float* B1v  = (const float*)d_in[3];
  const float* W2   = (const float*)d_in[4];
  const float* B2v  = (const float*)d_in[5];
  const float* Wr1  = (const float*)d_in[6];
  const float* br1  = (const float*)d_in[7];
  const float* Wr2  = (const float*)d_in[8];
  const float* br2  = (const float*)d_in[9];
  float* ws = (float*)d_ws;  // needs 4096*464*4 = 7.6 MB

  gcn_fused<<<Bsz, BDIM, 0, stream>>>(X, SUPP, W1, B1v, W2, B2v, ws);
  gcn_readout<<<Bsz / 16, BDIM, 0, stream>>>(ws, Wr1, br1, Wr2, br2, (float*)d_out);
}

// Round 3
// 648.181 us; speedup vs baseline: 1.5288x; 1.5288x over previous
//
#include <hip/hip_runtime.h>
#include <math.h>

// GCN fused kernel for MI355X (gfx950). B=4096, N=116, F_IN=116, HID=256, OUT=2.
//   h1 = relu(support @ (x @ W1) + b1)
//   h2 = relu(support @ (h1 @ W2) + b2)
//   r  = relu(h2.flat @ Wr1 + br1); out = log_softmax(r @ Wr2 + br2)
// R2: 512 threads (2 waves/SIMD), weight pre-transpose prologue into ws,
// incremental GEMM3 (no full-h1 buffer), readout fused into kernel 1.

#define BDIM 512

constexpr int Bsz = 4096;
constexpr int Nn  = 116;
constexpr int Fin = 116;
constexpr int HID = 256;
constexpr int SK  = 136;          // bf16 row stride (272 B -> bank rotation)
constexpr int NF4 = 3364;         // 116*116/4
constexpr int W1T_ELEMS = 256 * SK;   // 34816
constexpr int W2T_OFF   = W1T_ELEMS;  // W2T bf16 [4][264] after W1T

typedef __bf16 bf16;
typedef __bf16 bf16x4 __attribute__((ext_vector_type(4)));
typedef __bf16 bf16x8 __attribute__((ext_vector_type(8)));
typedef float  floatx4 __attribute__((ext_vector_type(4)));

// MFMA 16x16x32 bf16 layout: A-frag A[m=lane&15][k=(lane>>4)*8+j];
// B-frag BT[n=lane&15][k=(lane>>4)*8+j]; C/D col=lane&15, row=(lane>>4)*4+reg.

__global__ __launch_bounds__(1024) void prep_weights(
    const float* __restrict__ W1, const float* __restrict__ W2,
    bf16* __restrict__ WT)
{
  int j = blockIdx.x * 1024 + threadIdx.x;
  if (j < W1T_ELEMS) {                       // W1T[h][kk], kk>=116 zeroed
    int h = j / SK, kk = j - h * SK;
    WT[j] = (bf16)((kk < Fin) ? W1[kk * HID + h] : 0.f);
  } else if (j < W1T_ELEMS + 4 * 264) {      // W2T[n][k], k>=256 zeroed
    int t = j - W1T_ELEMS;
    int n = t / 264, k = t - n * 264;
    WT[j] = (bf16)((k < HID) ? W2[k * 4 + n] : 0.f);
  }
}

__global__ __launch_bounds__(BDIM, 2) void gcn_fused(
    const float* __restrict__ X, const float* __restrict__ SUPP,
    const bf16* __restrict__ WT,
    const float* __restrict__ B1v, const float* __restrict__ B2v,
    const float* __restrict__ Wr1, const float* __restrict__ br1,
    const float* __restrict__ Wr2, const float* __restrict__ br2,
    float* __restrict__ OUTP)
{
  // 146.4 KB LDS -> 1 block/CU, 8 waves (2/SIMD)
  __shared__ __align__(16) bf16 sx  [128 * SK];  // x_b   34816 B
  __shared__ __align__(16) bf16 ssup[128 * SK];  // sup_b 34816 B
  __shared__ __align__(16) bf16 swb [128 * SK];  // W1T chunk / xwT 34816 B
  __shared__ __align__(16) bf16 sh1c[128 * SK];  // h1 chunk (rows>=116 garbage ok)
  __shared__ __align__(16) bf16 sw2t[4 * 264];   // W2T 2112 B
  __shared__ __align__(16) bf16 stt [4 * SK];    // t^T  1088 B
  __shared__ float sh2[464];                     // h2 flat
  __shared__ float spart[8 * 64];                // readout partials

  const int b    = blockIdx.x;
  const int tid  = threadIdx.x;
  const int wid  = tid >> 6;
  const int lane = tid & 63;
  const int quad = lane >> 4;
  const int l16  = lane & 15;

  // ---- stage x_b, sup_b (fp32 -> bf16), coalesced float4 ----
  const float4* xg = (const float4*)(X    + (size_t)b * (Nn * Fin));
  const float4* sg = (const float4*)(SUPP + (size_t)b * (Nn * Fin));
  for (int i = tid; i < NF4; i += BDIM) {
    int m  = i / 29;
    int kq = (i - m * 29) * 4;
    float4 v = xg[i];
    bf16x4 p; p[0]=(bf16)v.x; p[1]=(bf16)v.y; p[2]=(bf16)v.z; p[3]=(bf16)v.w;
    *(bf16x4*)&sx[m * SK + kq] = p;
    float4 u = sg[i];
    bf16x4 q; q[0]=(bf16)u.x; q[1]=(bf16)u.y; q[2]=(bf16)u.z; q[3]=(bf16)u.w;
    *(bf16x4*)&ssup[m * SK + kq] = q;
  }
  // zero K-pad cols 116..135 of sx/ssup (NaN-safety: pad feeds MFMA K)
  for (int i = tid; i < 128 * 5; i += BDIM) {
    int m = i / 5, cc = 116 + (i - m * 5) * 4;
    bf16x4 z; z[0]=z[1]=z[2]=z[3]=(bf16)0.f;
    *(bf16x4*)&sx[m * SK + cc] = z;
    *(bf16x4*)&ssup[m * SK + cc] = z;
  }
  // stage W1T chunk 0 + W2T (flat coalesced copy, already transposed+padded)
  {
    const float4* wsrc = (const float4*)WT;
    float4* wdst = (float4*)swb;
    for (int i = tid; i < 2176; i += BDIM) wdst[i] = wsrc[i];
    const float4* w2src = (const float4*)(WT + W2T_OFF);
    if (tid < 132) ((float4*)sw2t)[tid] = w2src[tid];
  }

  const int wm = (wid & 1) * 64;    // wave m-base (2x4 wave grid)
  const int wn = (wid >> 1) * 32;   // wave n-base within 128-chunk

  floatx4 acc3; acc3[0]=acc3[1]=acc3[2]=acc3[3]=0.f;  // GEMM3 accum (16 rows/wave)

  for (int c = 0; c < 2; ++c) {
    if (c == 1) {
      // stage W1T chunk 1 (overwrites xwT(0): GEMM2(0) reads done pre-D)
      const float4* wsrc = (const float4*)(WT + 128 * SK);
      float4* wdst = (float4*)swb;
      for (int i = tid; i < 2176; i += BDIM) wdst[i] = wsrc[i];
      // GEMM3 chunk 0 overlapped with the copy
#pragma unroll
      for (int ks = 0; ks < 4; ++ks) {
        int k0 = ks * 32 + quad * 8;
        bf16x8 bfr = *(const bf16x8*)&sw2t[(l16 & 3) * 264 + k0];
        bf16x8 af  = *(const bf16x8*)&sh1c[(wid * 16 + l16) * SK + k0];
        acc3 = __builtin_amdgcn_mfma_f32_16x16x32_bf16(af, bfr, acc3, 0, 0, 0);
      }
    }
    __syncthreads();  // A: staging visible

    // GEMM1: xw_c = x @ W1_c  (M=128, N=128, K=128)
    floatx4 acc[4][2];
#pragma unroll
    for (int mt = 0; mt < 4; ++mt)
#pragma unroll
      for (int nt = 0; nt < 2; ++nt) { acc[mt][nt][0]=acc[mt][nt][1]=acc[mt][nt][2]=acc[mt][nt][3]=0.f; }
#pragma unroll
    for (int ks = 0; ks < 4; ++ks) {
      int k0 = ks * 32 + quad * 8;
      bf16x8 af[4], bfr[2];
#pragma unroll
      for (int mt = 0; mt < 4; ++mt)
        af[mt] = *(const bf16x8*)&sx[(wm + mt * 16 + l16) * SK + k0];
#pragma unroll
      for (int nt = 0; nt < 2; ++nt)
        bfr[nt] = *(const bf16x8*)&swb[(wn + nt * 16 + l16) * SK + k0];
#pragma unroll
      for (int mt = 0; mt < 4; ++mt)
#pragma unroll
        for (int nt = 0; nt < 2; ++nt)
          acc[mt][nt] = __builtin_amdgcn_mfma_f32_16x16x32_bf16(af[mt], bfr[nt], acc[mt][nt], 0, 0, 0);
    }
    __syncthreads();  // B: W1T reads done

    // write xw^T into swb (zero m-pad >=116 for GEMM2 K-pad safety)
#pragma unroll
    for (int mt = 0; mt < 4; ++mt)
#pragma unroll
      for (int nt = 0; nt < 2; ++nt) {
        int mb = wm + mt * 16 + quad * 4;
        int n  = wn + nt * 16 + l16;
        floatx4 a = acc[mt][nt];
        bf16x4 p;
        if (mb < Nn) { p[0]=(bf16)a[0]; p[1]=(bf16)a[1]; p[2]=(bf16)a[2]; p[3]=(bf16)a[3]; }
        else         { p[0]=p[1]=p[2]=p[3]=(bf16)0.f; }
        *(bf16x4*)&swb[n * SK + mb] = p;
      }
    __syncthreads();  // C

    // GEMM2: h1_c = relu(sup @ xw_c + b1_c)
#pragma unroll
    for (int mt = 0; mt < 4; ++mt)
#pragma unroll
      for (int nt = 0; nt < 2; ++nt) { acc[mt][nt][0]=acc[mt][nt][1]=acc[mt][nt][2]=acc[mt][nt][3]=0.f; }
#pragma unroll
    for (int ks = 0; ks < 4; ++ks) {
      int k0 = ks * 32 + quad * 8;
      bf16x8 af[4], bfr[2];
#pragma unroll
      for (int mt = 0; mt < 4; ++mt)
        af[mt] = *(const bf16x8*)&ssup[(wm + mt * 16 + l16) * SK + k0];
#pragma unroll
      for (int nt = 0; nt < 2; ++nt)
        bfr[nt] = *(const bf16x8*)&swb[(wn + nt * 16 + l16) * SK + k0];
#pragma unroll
      for (int mt = 0; mt < 4; ++mt)
#pragma unroll
        for (int nt = 0; nt < 2; ++nt)
          acc[mt][nt] = __builtin_amdgcn_mfma_f32_16x16x32_bf16(af[mt], bfr[nt], acc[mt][nt], 0, 0, 0);
    }
    // epilogue -> sh1c (rows >=116 finite garbage, discarded later)
#pragma unroll
    for (int mt = 0; mt < 4; ++mt)
#pragma unroll
      for (int nt = 0; nt < 2; ++nt) {
        int mb   = wm + mt * 16 + quad * 4;
        int coll = wn + nt * 16 + l16;
        float bb = B1v[c * 128 + coll];
        floatx4 a = acc[mt][nt];
#pragma unroll
        for (int r = 0; r < 4; ++r)
          sh1c[(mb + r) * SK + coll] = (bf16)fmaxf(a[r] + bb, 0.f);
      }
    __syncthreads();  // D: h1c visible
  }

  // GEMM3 chunk 1: t += h1c @ W2[128:256,:]
#pragma unroll
  for (int ks = 0; ks < 4; ++ks) {
    int k0 = ks * 32 + quad * 8;
    bf16x8 bfr = *(const bf16x8*)&sw2t[(l16 & 3) * 264 + 128 + k0];
    bf16x8 af  = *(const bf16x8*)&sh1c[(wid * 16 + l16) * SK + k0];
    acc3 = __builtin_amdgcn_mfma_f32_16x16x32_bf16(af, bfr, acc3, 0, 0, 0);
  }
  // write t^T (zero pad m>=116)
  {
    int mb = wid * 16 + quad * 4;
    bf16x4 p;
    if (mb < Nn) { p[0]=(bf16)acc3[0]; p[1]=(bf16)acc3[1]; p[2]=(bf16)acc3[2]; p[3]=(bf16)acc3[3]; }
    else         { p[0]=p[1]=p[2]=p[3]=(bf16)0.f; }
    if (l16 < 4) *(bf16x4*)&stt[l16 * SK + mb] = p;
  }
  __syncthreads();  // E

  // GEMM4: h2 = relu(sup @ t + b2)  (16 rows/wave)
  floatx4 acc4; acc4[0]=acc4[1]=acc4[2]=acc4[3]=0.f;
#pragma unroll
  for (int ks = 0; ks < 4; ++ks) {
    int k0 = ks * 32 + quad * 8;
    bf16x8 af  = *(const bf16x8*)&ssup[(wid * 16 + l16) * SK + k0];
    bf16x8 bfr = *(const bf16x8*)&stt[(l16 & 3) * SK + k0];
    acc4 = __builtin_amdgcn_mfma_f32_16x16x32_bf16(af, bfr, acc4, 0, 0, 0);
  }
  if (l16 < 4) {
    float bb = B2v[l16];
#pragma unroll
    for (int r = 0; r < 4; ++r) {
      int m = wid * 16 + quad * 4 + r;
      if (m < Nn) sh2[m * 4 + l16] = fmaxf(acc4[r] + bb, 0.f);
    }
  }
  __syncthreads();  // F

  // readout: r = relu(flat @ Wr1 + br1); out = log_softmax(r @ Wr2 + br2)
  {
    int j   = tid & 63;      // output unit
    int ksl = tid >> 6;      // k-split 0..7 (58 k each)
    int kb  = ksl * 58;
    float p = 0.f;
#pragma unroll 2
    for (int kk = 0; kk < 58; ++kk)
      p = fmaf(sh2[kb + kk], Wr1[(kb + kk) * 64 + j], p);  // Wr1 coalesced, L2-hot
    spart[ksl * 64 + j] = p;
  }
  __syncthreads();  // G
  if (tid < 64) {
    int j = tid;
    float r = 0.f;
#pragma unroll
    for (int s = 0; s < 8; ++s) r += spart[s * 64 + j];
    r = fmaxf(r + br1[j], 0.f);
    float p0 = r * Wr2[j * 2 + 0];
    float p1 = r * Wr2[j * 2 + 1];
#pragma unroll
    for (int off = 32; off > 0; off >>= 1) {
      p0 += __shfl_xor(p0, off, 64);
      p1 += __shfl_xor(p1, off, 64);
    }
    float l0 = p0 + br2[0], l1 = p1 + br2[1];
    float mx  = fmaxf(l0, l1);
    float lse = mx + logf(expf(l0 - mx) + expf(l1 - mx));
    if (j < 2) OUTP[(size_t)b * 2 + j] = (j ? l1 : l0) - lse;
  }
}

extern "C" void kernel_launch(void* const* d_in, const int* in_sizes, int n_in,
                              void* d_out, int out_size, void* d_ws, size_t ws_size,
                              hipStream_t stream) {
  const float* X    = (const float*)d_in[0];
  const float* SUPP = (const float*)d_in[1];
  const float* W1   = (const float*)d_in[2];
  const float* B1v  = (const float*)d_in[3];
  const float* W2   = (const float*)d_in[4];
  const float* B2v  = (const float*)d_in[5];
  const float* Wr1  = (const float*)d_in[6];
  const float* br1  = (const float*)d_in[7];
  const float* Wr2  = (const float*)d_in[8];
  const float* br2  = (const float*)d_in[9];
  bf16* WT = (bf16*)d_ws;  // 71.7 KB: W1T [256][136] + W2T [4][264]

  prep_weights<<<36, 1024, 0, stream>>>(W1, W2, WT);
  gcn_fused<<<Bsz, BDIM, 0, stream>>>(X, SUPP, WT, B1v, B2v,
                                      Wr1, br1, Wr2, br2, (float*)d_out);
}

// Round 4
// 607.173 us; speedup vs baseline: 1.6321x; 1.0675x over previous
//
#include <hip/hip_runtime.h>
#include <math.h>

// GCN fused kernel for MI355X (gfx950). B=4096, N=116, F_IN=116, HID=256, OUT=2.
// R4: LDS cut to ~75 KB -> 2 blocks/CU (x fragments loaded from global in the
// GEMM1 k-loop; swb aliased for W1T / xwT / h1c). 512 threads, launch_bounds
// (512,4) to hold VGPR <= 128 so occupancy is LDS-limited (2 blocks/CU).

#define BDIM 512

constexpr int Bsz = 4096;
constexpr int Nn  = 116;
constexpr int Fin = 116;
constexpr int HID = 256;
constexpr int SK  = 136;            // bf16 row stride (272 B -> bank rotation)
constexpr int NF4 = 3364;           // 116*116/4
constexpr int W1T_ELEMS = 256 * SK; // 34816
constexpr int W2T_OFF   = W1T_ELEMS;

typedef __bf16 bf16;
typedef __bf16 bf16x4 __attribute__((ext_vector_type(4)));
typedef __bf16 bf16x8 __attribute__((ext_vector_type(8)));
typedef float  floatx4 __attribute__((ext_vector_type(4)));

// MFMA 16x16x32 bf16 layout: A-frag A[m=lane&15][k=(lane>>4)*8+j];
// B-frag BT[n=lane&15][k=(lane>>4)*8+j]; C/D col=lane&15, row=(lane>>4)*4+reg.

__global__ __launch_bounds__(1024) void prep_weights(
    const float* __restrict__ W1, const float* __restrict__ W2,
    bf16* __restrict__ WT)
{
  int j = blockIdx.x * 1024 + threadIdx.x;
  if (j < W1T_ELEMS) {                       // W1T[h][kk], kk>=116 zeroed
    int h = j / SK, kk = j - h * SK;
    WT[j] = (bf16)((kk < Fin) ? W1[kk * HID + h] : 0.f);
  } else if (j < W1T_ELEMS + 4 * 264) {      // W2T[n][k], k>=256 zeroed
    int t = j - W1T_ELEMS;
    int n = t / 264, k = t - n * 264;
    WT[j] = (bf16)((k < HID) ? W2[k * 4 + n] : 0.f);
  }
}

__device__ inline bf16x8 cvt8(const float* p) {
  float4 v0 = *(const float4*)p;
  float4 v1 = *(const float4*)(p + 4);
  bf16x8 f;
  f[0]=(bf16)v0.x; f[1]=(bf16)v0.y; f[2]=(bf16)v0.z; f[3]=(bf16)v0.w;
  f[4]=(bf16)v1.x; f[5]=(bf16)v1.y; f[6]=(bf16)v1.z; f[7]=(bf16)v1.w;
  return f;
}

__global__ __launch_bounds__(BDIM, 4) void gcn_fused(
    const float* __restrict__ X, const float* __restrict__ SUPP,
    const bf16* __restrict__ WT,
    const float* __restrict__ B1v, const float* __restrict__ B2v,
    const float* __restrict__ Wr1, const float* __restrict__ br1,
    const float* __restrict__ Wr2, const float* __restrict__ br2,
    float* __restrict__ OUTP)
{
  // 76,736 B LDS -> 2 blocks/CU (16 waves/CU)
  __shared__ __align__(16) bf16 ssup[128 * SK];  // sup_b          34816 B
  __shared__ __align__(16) bf16 swb [128 * SK];  // W1T/xwT/h1c    34816 B
  __shared__ __align__(16) bf16 sw2t[4 * 264];   // W2T             2112 B
  __shared__ __align__(16) bf16 stt [4 * SK];    // t^T             1088 B
  __shared__ float sh2[464];                     //                 1856 B
  __shared__ float spart[8 * 64];                //                 2048 B

  const int b    = blockIdx.x;
  const int tid  = threadIdx.x;
  const int wid  = tid >> 6;
  const int lane = tid & 63;
  const int quad = lane >> 4;
  const int l16  = lane & 15;

  // wave grid: 4 m-groups x 2 n-groups; wave tile 32(m) x 64(n)
  const int wm = (wid & 3) * 32;
  const int wn = (wid >> 2) * 64;

  // ---- stage support (fp32 -> bf16), coalesced float4 ----
  const float4* sg = (const float4*)(SUPP + (size_t)b * (Nn * Fin));
  for (int i = tid; i < NF4; i += BDIM) {
    int m  = i / 29;
    int kq = (i - m * 29) * 4;
    float4 u = sg[i];
    bf16x4 q; q[0]=(bf16)u.x; q[1]=(bf16)u.y; q[2]=(bf16)u.z; q[3]=(bf16)u.w;
    *(bf16x4*)&ssup[m * SK + kq] = q;
  }
  {
    bf16x4 z; z[0]=z[1]=z[2]=z[3]=(bf16)0.f;
    // zero K-pad cols 116..135, all 128 rows
    for (int i = tid; i < 128 * 5; i += BDIM) {
      int m = i / 5, cc = 116 + (i - m * 5) * 4;
      *(bf16x4*)&ssup[m * SK + cc] = z;
    }
    // zero garbage rows 116..127 (cols 0..115) — NaN insurance
    for (int i = tid; i < 12 * 29; i += BDIM) {
      int r = 116 + i / 29, cc = (i - (i / 29) * 29) * 4;
      *(bf16x4*)&ssup[r * SK + cc] = z;
    }
  }
  // stage W1T chunk 0 + W2T (flat coalesced; already transposed+padded)
  for (int i = tid; i < 2176; i += BDIM)
    ((float4*)swb)[i] = ((const float4*)WT)[i];
  if (tid < 132) ((float4*)sw2t)[tid] = ((const float4*)(WT + W2T_OFF))[tid];
  __syncthreads();  // S0

  const float* xrow = X + (size_t)b * (Nn * Fin);
  floatx4 acc3; acc3[0]=acc3[1]=acc3[2]=acc3[3]=0.f;  // GEMM3 acc (16 rows/wave)

  for (int c = 0; c < 2; ++c) {
    if (c == 1) {
      for (int i = tid; i < 2176; i += BDIM)  // stage W1T chunk 1
        ((float4*)swb)[i] = ((const float4*)(WT + 128 * SK))[i];
      __syncthreads();  // S6
    }

    // GEMM1: xw_c = x @ W1_c  (M=128, N=128, K=128); A from global (L1/L2-hot)
    floatx4 acc[2][4];
#pragma unroll
    for (int mt = 0; mt < 2; ++mt)
#pragma unroll
      for (int nt = 0; nt < 4; ++nt) { acc[mt][nt][0]=acc[mt][nt][1]=acc[mt][nt][2]=acc[mt][nt][3]=0.f; }
#pragma unroll
    for (int ks = 0; ks < 4; ++ks) {
      const int k0 = ks * 32 + quad * 8;
      bf16x8 af[2];
#pragma unroll
      for (int mt = 0; mt < 2; ++mt) {
        int row  = wm + mt * 16 + l16;
        int rowc = row < Nn ? row : (Nn - 1);      // clamp: rows>=116 discarded later
        const float* p = xrow + rowc * Fin + k0;
        if (ks < 3) {
          af[mt] = cvt8(p);                         // fully in-row (k0+8 <= 96+8 <= 116? yes for ks<3: k0<=88)
        } else {
          bf16x8 f;
#pragma unroll
          for (int j = 0; j < 8; ++j)
            f[j] = (k0 + j < Fin) ? (bf16)p[j] : (bf16)0.f;  // K-tail guard
          af[mt] = f;
        }
      }
      bf16x8 bfr[4];
#pragma unroll
      for (int nt = 0; nt < 4; ++nt)
        bfr[nt] = *(const bf16x8*)&swb[(wn + nt * 16 + l16) * SK + k0];
#pragma unroll
      for (int mt = 0; mt < 2; ++mt)
#pragma unroll
        for (int nt = 0; nt < 4; ++nt)
          acc[mt][nt] = __builtin_amdgcn_mfma_f32_16x16x32_bf16(af[mt], bfr[nt], acc[mt][nt], 0, 0, 0);
    }
    __syncthreads();  // S1: W1T reads done

    // write xw^T into swb (zero m-pad >=116: m is GEMM2's K)
#pragma unroll
    for (int mt = 0; mt < 2; ++mt)
#pragma unroll
      for (int nt = 0; nt < 4; ++nt) {
        int mb = wm + mt * 16 + quad * 4;
        int n  = wn + nt * 16 + l16;
        floatx4 a = acc[mt][nt];
        bf16x4 p;
        if (mb < Nn) { p[0]=(bf16)a[0]; p[1]=(bf16)a[1]; p[2]=(bf16)a[2]; p[3]=(bf16)a[3]; }
        else         { p[0]=p[1]=p[2]=p[3]=(bf16)0.f; }
        *(bf16x4*)&swb[n * SK + mb] = p;
      }
    __syncthreads();  // S2: xwT visible

    // GEMM2: h1_c = relu(sup @ xw_c + b1_c)
#pragma unroll
    for (int mt = 0; mt < 2; ++mt)
#pragma unroll
      for (int nt = 0; nt < 4; ++nt) { acc[mt][nt][0]=acc[mt][nt][1]=acc[mt][nt][2]=acc[mt][nt][3]=0.f; }
#pragma unroll
    for (int ks = 0; ks < 4; ++ks) {
      const int k0 = ks * 32 + quad * 8;
      bf16x8 af[2], bfr[4];
#pragma unroll
      for (int mt = 0; mt < 2; ++mt)
        af[mt] = *(const bf16x8*)&ssup[(wm + mt * 16 + l16) * SK + k0];
#pragma unroll
      for (int nt = 0; nt < 4; ++nt)
        bfr[nt] = *(const bf16x8*)&swb[(wn + nt * 16 + l16) * SK + k0];
#pragma unroll
      for (int mt = 0; mt < 2; ++mt)
#pragma unroll
        for (int nt = 0; nt < 4; ++nt)
          acc[mt][nt] = __builtin_amdgcn_mfma_f32_16x16x32_bf16(af[mt], bfr[nt], acc[mt][nt], 0, 0, 0);
    }
    __syncthreads();  // S3: xwT reads done (swb about to be overwritten)

    // write h1_c into swb as A-layout [m][k_local] (+bias, relu)
#pragma unroll
    for (int mt = 0; mt < 2; ++mt)
#pragma unroll
      for (int nt = 0; nt < 4; ++nt) {
        int mb   = wm + mt * 16 + quad * 4;
        int coll = wn + nt * 16 + l16;
        float bb = B1v[c * 128 + coll];
        floatx4 a = acc[mt][nt];
#pragma unroll
        for (int r = 0; r < 4; ++r)
          swb[(mb + r) * SK + coll] = (bf16)fmaxf(a[r] + bb, 0.f);
      }
    __syncthreads();  // S4: h1c visible

    // GEMM3 partial: t += h1c @ W2[c*128 : c*128+128, :]
#pragma unroll
    for (int ks = 0; ks < 4; ++ks) {
      const int k0 = ks * 32 + quad * 8;
      bf16x8 bfr = *(const bf16x8*)&sw2t[(l16 & 3) * 264 + c * 128 + k0];
      bf16x8 af  = *(const bf16x8*)&swb[(wid * 16 + l16) * SK + k0];
      acc3 = __builtin_amdgcn_mfma_f32_16x16x32_bf16(af, bfr, acc3, 0, 0, 0);
    }
    if (c == 0) __syncthreads();  // S5: h1c reads done before restage
  }

  // write t^T (zero pad m>=116: m is GEMM4's K)
  {
    int mb = wid * 16 + quad * 4;
    bf16x4 p;
    if (mb < Nn) { p[0]=(bf16)acc3[0]; p[1]=(bf16)acc3[1]; p[2]=(bf16)acc3[2]; p[3]=(bf16)acc3[3]; }
    else         { p[0]=p[1]=p[2]=p[3]=(bf16)0.f; }
    if (l16 < 4) *(bf16x4*)&stt[l16 * SK + mb] = p;
  }
  __syncthreads();  // S7

  // GEMM4: h2 = relu(sup @ t + b2)  (16 rows/wave)
  floatx4 acc4; acc4[0]=acc4[1]=acc4[2]=acc4[3]=0.f;
#pragma unroll
  for (int ks = 0; ks < 4; ++ks) {
    const int k0 = ks * 32 + quad * 8;
    bf16x8 af  = *(const bf16x8*)&ssup[(wid * 16 + l16) * SK + k0];
    bf16x8 bfr = *(const bf16x8*)&stt[(l16 & 3) * SK + k0];
    acc4 = __builtin_amdgcn_mfma_f32_16x16x32_bf16(af, bfr, acc4, 0, 0, 0);
  }
  if (l16 < 4) {
    float bb = B2v[l16];
#pragma unroll
    for (int r = 0; r < 4; ++r) {
      int m = wid * 16 + quad * 4 + r;
      if (m < Nn) sh2[m * 4 + l16] = fmaxf(acc4[r] + bb, 0.f);
    }
  }
  __syncthreads();  // S8

  // readout: r = relu(flat @ Wr1 + br1); out = log_softmax(r @ Wr2 + br2)
  {
    int j   = tid & 63;      // output unit
    int ksl = tid >> 6;      // k-split 0..7 (58 k each)
    int kb  = ksl * 58;
    float p = 0.f;
#pragma unroll 2
    for (int kk = 0; kk < 58; ++kk)
      p = fmaf(sh2[kb + kk], Wr1[(kb + kk) * 64 + j], p);  // coalesced, L2-hot
    spart[ksl * 64 + j] = p;
  }
  __syncthreads();  // S9
  if (tid < 64) {
    int j = tid;
    float r = 0.f;
#pragma unroll
    for (int s = 0; s < 8; ++s) r += spart[s * 64 + j];
    r = fmaxf(r + br1[j], 0.f);
    float p0 = r * Wr2[j * 2 + 0];
    float p1 = r * Wr2[j * 2 + 1];
#pragma unroll
    for (int off = 32; off > 0; off >>= 1) {
      p0 += __shfl_xor(p0, off, 64);
      p1 += __shfl_xor(p1, off, 64);
    }
    float l0 = p0 + br2[0], l1 = p1 + br2[1];
    float mx  = fmaxf(l0, l1);
    float lse = mx + logf(expf(l0 - mx) + expf(l1 - mx));
    if (j < 2) OUTP[(size_t)b * 2 + j] = (j ? l1 : l0) - lse;
  }
}

extern "C" void kernel_launch(void* const* d_in, const int* in_sizes, int n_in,
                              void* d_out, int out_size, void* d_ws, size_t ws_size,
                              hipStream_t stream) {
  const float* X    = (const float*)d_in[0];
  const float* SUPP = (const float*)d_in[1];
  const float* W1   = (const float*)d_in[2];
  const float* B1v  = (const float*)d_in[3];
  const float* W2   = (const float*)d_in[4];
  const float* B2v  = (const float*)d_in[5];
  const float* Wr1  = (const float*)d_in[6];
  const float* br1  = (const float*)d_in[7];
  const float* Wr2  = (const float*)d_in[8];
  const float* br2  = (const float*)d_in[9];
  bf16* WT = (bf16*)d_ws;  // 71.7 KB: W1T [256][136] + W2T [4][264]

  prep_weights<<<36, 1024, 0, stream>>>(W1, W2, WT);
  gcn_fused<<<Bsz, BDIM, 0, stream>>>(X, SUPP, WT, B1v, B2v,
                                      Wr1, br1, Wr2, br2, (float*)d_out);
}